// Round 1
// baseline (5679.598 us; speedup 1.0000x reference)
//
#include <hip/hip_runtime.h>
#include <hip/hip_bf16.h>

typedef short bf16x8 __attribute__((ext_vector_type(8)));
typedef float f32x4 __attribute__((ext_vector_type(4)));

__device__ __forceinline__ unsigned short f2bf(float f) {
    unsigned int u = __float_as_uint(f);
    u = (u + 0x7FFFu + ((u >> 16) & 1u)) >> 16;
    return (unsigned short)u;
}
__device__ __forceinline__ float bf2f(unsigned short h) {
    return __uint_as_float(((unsigned int)h) << 16);
}

// ---------------- init: zero agg (=d_out), deg = 1 (self-loop) ----------------
__global__ __launch_bounds__(256) void init_k(float4* __restrict__ agg4,
                                              float* __restrict__ deg, int N) {
    int i = blockIdx.x * 256 + threadIdx.x;
    if (i < N * 32) agg4[i] = make_float4(0.f, 0.f, 0.f, 0.f);
    if (i < N) deg[i] = 1.0f;
}

// ---------------- degree accumulation ----------------
__global__ __launch_bounds__(256) void deg_k(const int* __restrict__ ei,
                                             const float* __restrict__ ew,
                                             float* __restrict__ deg, int E) {
    int e = blockIdx.x * 256 + threadIdx.x;
    if (e < E) unsafeAtomicAdd(&deg[ei[E + e]], ew[e]);
}

// ---------------- dinv = deg>0 ? rsqrt(deg) : 0  (in place) ----------------
__global__ __launch_bounds__(256) void dinv_k(float* __restrict__ deg, int N) {
    int i = blockIdx.x * 256 + threadIdx.x;
    if (i < N) {
        float d = deg[i];
        deg[i] = d > 0.f ? rsqrtf(d) : 0.f;
    }
}

// ---------------- GEMM: out[M x 128] = A[M x 128] @ W[128 x 128]^T ----------------
// W row-major [out_ch][in_ch]; MFMA 16x16x32 bf16; block = 256 thr = 4 waves,
// 64 rows/block (16/wave), full 128-col output per wave (8 n-tiles).
template <bool IN_BF16, bool BIAS, bool RELU, bool OUT_BF16>
__global__ __launch_bounds__(256) void gemm_k128(const void* __restrict__ Ain,
                                                 const float* __restrict__ W,
                                                 const float* __restrict__ bias,
                                                 void* __restrict__ Out, int M) {
    // LDS W as bf16, padded 128 -> 136 (272B row stride => bank offset 4/row,
    // conflict-free-enough for ds_read_b128: 2-way aliasing is free)
    __shared__ __align__(16) unsigned short Wl[128 * 136];
    const int tid = threadIdx.x;

    // stage W (16384 fp32) -> LDS bf16, coalesced float4 loads
#pragma unroll
    for (int i = 0; i < 16; ++i) {
        int e4 = i * 256 + tid;           // float4 index
        float4 v = ((const float4*)W)[e4];
        int e = e4 * 4;
        int r = e >> 7, c = e & 127;
        unsigned short* p = &Wl[r * 136 + c];
        p[0] = f2bf(v.x); p[1] = f2bf(v.y); p[2] = f2bf(v.z); p[3] = f2bf(v.w);
    }
    __syncthreads();

    const int wave = tid >> 6, lane = tid & 63;
    const int m = lane & 15, quad = lane >> 4;
    const int rowBase = blockIdx.x * 64 + wave * 16;
    int arow = rowBase + m;
    int arowc = arow < M ? arow : (M - 1);  // clamp loads; stores masked

    bf16x8 afrag[4];
    if constexpr (IN_BF16) {
        const unsigned short* A = (const unsigned short*)Ain;
        const unsigned short* pa = A + (size_t)arowc * 128 + quad * 8;
#pragma unroll
        for (int kc = 0; kc < 4; ++kc)
            afrag[kc] = *(const bf16x8*)(pa + kc * 32);
    } else {
        const float* A = (const float*)Ain;
        const float* pa = A + (size_t)arowc * 128 + quad * 8;
#pragma unroll
        for (int kc = 0; kc < 4; ++kc) {
            float4 v0 = *(const float4*)(pa + kc * 32);
            float4 v1 = *(const float4*)(pa + kc * 32 + 4);
            bf16x8 f;
            f[0] = (short)f2bf(v0.x); f[1] = (short)f2bf(v0.y);
            f[2] = (short)f2bf(v0.z); f[3] = (short)f2bf(v0.w);
            f[4] = (short)f2bf(v1.x); f[5] = (short)f2bf(v1.y);
            f[6] = (short)f2bf(v1.z); f[7] = (short)f2bf(v1.w);
            afrag[kc] = f;
        }
    }

#pragma unroll
    for (int nt = 0; nt < 8; ++nt) {
        f32x4 acc = {0.f, 0.f, 0.f, 0.f};
        const unsigned short* wb = &Wl[(nt * 16 + m) * 136 + quad * 8];
#pragma unroll
        for (int kc = 0; kc < 4; ++kc) {
            bf16x8 bfrag = *(const bf16x8*)(wb + kc * 32);
            acc = __builtin_amdgcn_mfma_f32_16x16x32_bf16(afrag[kc], bfrag, acc, 0, 0, 0);
        }
        // epilogue: D layout col = lane&15, row = quad*4 + r
        const int col = nt * 16 + m;
        float bv = 0.f;
        if constexpr (BIAS) bv = bias[col];
#pragma unroll
        for (int r = 0; r < 4; ++r) {
            int row = rowBase + quad * 4 + r;
            if (row < M) {
                float v = acc[r] + bv;
                if constexpr (RELU) v = fmaxf(v, 0.f);
                if constexpr (OUT_BF16)
                    ((unsigned short*)Out)[(size_t)row * 128 + col] = f2bf(v);
                else
                    ((float*)Out)[(size_t)row * 128 + col] = v;
            }
        }
    }
}

// ---------------- edge scatter: agg[dst] += h[src] * norm ----------------
// 32 threads per edge, 4 channels each (ushort4 gather, 4x f32 atomics)
__global__ __launch_bounds__(256) void scatter_k(const int* __restrict__ ei,
                                                 const float* __restrict__ ew,
                                                 const float* __restrict__ dinv,
                                                 const unsigned short* __restrict__ h,
                                                 float* __restrict__ agg, int E) {
    int idx = blockIdx.x * 256 + threadIdx.x;
    int e = idx >> 5;
    if (e >= E) return;
    int cg = (idx & 31) * 4;
    int src = ei[e];
    int dst = ei[E + e];
    float nrm = dinv[src] * ew[e] * dinv[dst];
    ushort4 hv = *(const ushort4*)(h + (size_t)src * 128 + cg);
    float* ap = agg + (size_t)dst * 128 + cg;
    unsafeAtomicAdd(ap + 0, bf2f(hv.x) * nrm);
    unsafeAtomicAdd(ap + 1, bf2f(hv.y) * nrm);
    unsafeAtomicAdd(ap + 2, bf2f(hv.z) * nrm);
    unsafeAtomicAdd(ap + 3, bf2f(hv.w) * nrm);
}

// ---------------- post: h2 = bf16(relu(agg + dinv^2 * h + b_conv)) ----------------
__global__ __launch_bounds__(256) void post_k(const float* __restrict__ agg,
                                              const unsigned short* __restrict__ h,
                                              const float* __restrict__ dinv,
                                              const float* __restrict__ bconv,
                                              unsigned short* __restrict__ h2, int N) {
    int i4 = blockIdx.x * 256 + threadIdx.x;  // one float4 per thread
    if (i4 >= N * 32) return;
    int node = i4 >> 5;
    int c = (i4 & 31) * 4;
    float di = dinv[node];
    float sl = di * di;
    float4 a = ((const float4*)agg)[i4];
    ushort4 hv = *(const ushort4*)(h + (size_t)node * 128 + c);
    float4 b = *(const float4*)(bconv + c);
    ushort4 o;
    o.x = f2bf(fmaxf(a.x + sl * bf2f(hv.x) + b.x, 0.f));
    o.y = f2bf(fmaxf(a.y + sl * bf2f(hv.y) + b.y, 0.f));
    o.z = f2bf(fmaxf(a.z + sl * bf2f(hv.z) + b.z, 0.f));
    o.w = f2bf(fmaxf(a.w + sl * bf2f(hv.w) + b.w, 0.f));
    *(ushort4*)(h2 + (size_t)node * 128 + c) = o;
}

extern "C" void kernel_launch(void* const* d_in, const int* in_sizes, int n_in,
                              void* d_out, int out_size, void* d_ws, size_t ws_size,
                              hipStream_t stream) {
    const float* x  = (const float*)d_in[0];
    const int* ei   = (const int*)d_in[1];
    const float* ew = (const float*)d_in[2];
    const float* Wc = (const float*)d_in[3];
    const float* bc = (const float*)d_in[4];
    const float* Wf = (const float*)d_in[5];
    const float* bf = (const float*)d_in[6];
    const float* W2 = (const float*)d_in[7];
    const float* b2 = (const float*)d_in[8];
    float* out = (float*)d_out;

    const int N = in_sizes[0] / 128;
    const int E = in_sizes[2];

    char* ws = (char*)d_ws;
    float* deg = (float*)ws;  // N floats; becomes dinv in place
    size_t degBytes = (((size_t)N * 4) + 255) & ~(size_t)255;
    unsigned short* h  = (unsigned short*)(ws + degBytes);   // N*128 bf16
    unsigned short* h2 = h + (size_t)N * 128;                // N*128 bf16
    float* agg = out;  // reuse d_out as fp32 agg scratch (consumed before GEMM3)

    const int nElem4 = N * 32;
    init_k<<<(nElem4 + 255) / 256, 256, 0, stream>>>((float4*)agg, deg, N);
    deg_k<<<(E + 255) / 256, 256, 0, stream>>>(ei, ew, deg, E);
    dinv_k<<<(N + 255) / 256, 256, 0, stream>>>(deg, N);

    // h = bf16(x @ W_conv^T)  (bias added after aggregation)
    gemm_k128<false, false, false, true>
        <<<(N + 63) / 64, 256, 0, stream>>>(x, Wc, nullptr, h, N);

    long long totScatter = (long long)E * 32;
    scatter_k<<<(int)((totScatter + 255) / 256), 256, 0, stream>>>(ei, ew, deg, h, agg, E);

    post_k<<<(nElem4 + 255) / 256, 256, 0, stream>>>(agg, h, deg, bc, h2, N);

    // h = bf16(relu(h2 @ W_fc^T + b_fc))   (reuse h buffer)
    gemm_k128<true, true, true, true>
        <<<(N + 63) / 64, 256, 0, stream>>>(h2, Wf, bf, h, N);

    // out = h @ W_fc2^T + b_fc2  (fp32 out; d_out's agg role already consumed)
    gemm_k128<true, true, false, false>
        <<<(N + 63) / 64, 256, 0, stream>>>(h, W2, b2, out, N);
}

// Round 2
// 906.882 us; speedup vs baseline: 6.2628x; 6.2628x over previous
//
#include <hip/hip_runtime.h>
#include <hip/hip_bf16.h>

typedef short bf16x8 __attribute__((ext_vector_type(8)));
typedef float f32x4 __attribute__((ext_vector_type(4)));

__device__ __forceinline__ unsigned short f2bf(float f) {
    unsigned int u = __float_as_uint(f);
    u = (u + 0x7FFFu + ((u >> 16) & 1u)) >> 16;
    return (unsigned short)u;
}
__device__ __forceinline__ float bf2f(unsigned short h) {
    return __uint_as_float(((unsigned int)h) << 16);
}

// ---------------- init: deg = 1 (self-loop weight), cnt = 0 ----------------
__global__ __launch_bounds__(256) void init_k(float* __restrict__ deg,
                                              int* __restrict__ cnt, int N) {
    int i = blockIdx.x * 256 + threadIdx.x;
    if (i < N) { deg[i] = 1.0f; cnt[i] = 0; }
}

// ---------------- histogram by dst + weighted degree ----------------
__global__ __launch_bounds__(256) void hist_k(const int* __restrict__ ei,
                                              const float* __restrict__ ew,
                                              int* __restrict__ cnt,
                                              float* __restrict__ deg, int E) {
    int e = blockIdx.x * 256 + threadIdx.x;
    if (e < E) {
        int dst = ei[E + e];
        atomicAdd(&cnt[dst], 1);
        unsafeAtomicAdd(&deg[dst], ew[e]);
    }
}

// ---------------- scan pass 1: per-block exclusive scan of cnt ----------------
__global__ __launch_bounds__(256) void scan1_k(const int* __restrict__ cnt,
                                               int* __restrict__ rowPtr,
                                               int* __restrict__ bsum, int N) {
    __shared__ int s[256];
    int t = threadIdx.x;
    int i = blockIdx.x * 256 + t;
    int v = (i < N) ? cnt[i] : 0;
    s[t] = v;
    __syncthreads();
#pragma unroll
    for (int off = 1; off < 256; off <<= 1) {
        int x = (t >= off) ? s[t - off] : 0;
        __syncthreads();
        s[t] += x;
        __syncthreads();
    }
    if (i < N) rowPtr[i] = s[t] - v;          // exclusive within block
    if (t == 255) bsum[blockIdx.x] = s[255];  // block total
}

// ---------------- scan pass 2: single-block scan of block sums ----------------
__global__ __launch_bounds__(1024) void scan2_k(int* __restrict__ bsum, int nB) {
    __shared__ int s[1024];
    int t = threadIdx.x;
    int v = (t < nB) ? bsum[t] : 0;
    s[t] = v;
    __syncthreads();
#pragma unroll
    for (int off = 1; off < 1024; off <<= 1) {
        int x = (t >= off) ? s[t - off] : 0;
        __syncthreads();
        s[t] += x;
        __syncthreads();
    }
    if (t < nB) bsum[t] = s[t] - v;  // exclusive
}

// ---------------- scan pass 3: add offsets, init cursor, dinv in place ----------------
__global__ __launch_bounds__(256) void scan3_k(int* __restrict__ rowPtr,
                                               const int* __restrict__ bsum,
                                               int* __restrict__ cursor,
                                               float* __restrict__ deg,
                                               int N, int E) {
    int i = blockIdx.x * 256 + threadIdx.x;
    if (i < N) {
        int rp = rowPtr[i] + bsum[blockIdx.x];
        rowPtr[i] = rp;
        cursor[i] = rp;
        float d = deg[i];
        deg[i] = d > 0.f ? rsqrtf(d) : 0.f;
    }
    if (i == 0) rowPtr[N] = E;
}

// ---------------- fill: csr[pos] = {src, norm} binned by dst ----------------
__global__ __launch_bounds__(256) void fill_k(const int* __restrict__ ei,
                                              const float* __restrict__ ew,
                                              const float* __restrict__ dinv,
                                              int* __restrict__ cursor,
                                              int2* __restrict__ csr, int E) {
    int e = blockIdx.x * 256 + threadIdx.x;
    if (e >= E) return;
    int src = ei[e];
    int dst = ei[E + e];
    float nrm = dinv[src] * ew[e] * dinv[dst];
    int p = atomicAdd(&cursor[dst], 1);
    csr[p] = make_int2(src, __float_as_int(nrm));
}

// ---------------- aggregate: one wave per node, lane = 2 channels ----------------
// h2[n] = bf16(relu( sum_{e in bin(n)} h[src_e]*nrm_e + dinv[n]^2*h[n] + b_conv ))
__global__ __launch_bounds__(256) void agg_k(const int* __restrict__ rowPtr,
                                             const int2* __restrict__ csr,
                                             const unsigned short* __restrict__ h,
                                             const float* __restrict__ dinv,
                                             const float* __restrict__ bconv,
                                             unsigned short* __restrict__ h2, int N) {
    int lane = threadIdx.x & 63;
    int n = blockIdx.x * 4 + (threadIdx.x >> 6);
    if (n >= N) return;
    int s = rowPtr[n], e = rowPtr[n + 1];
    float a0 = 0.f, a1 = 0.f;
    for (int j = s; j < e; ++j) {
        int2 pr = csr[j];                       // same addr across wave: broadcast
        float nrm = __int_as_float(pr.y);
        ushort2 hv = *(const ushort2*)(h + (size_t)pr.x * 128 + lane * 2);
        a0 += bf2f(hv.x) * nrm;
        a1 += bf2f(hv.y) * nrm;
    }
    float di = dinv[n];
    float sl = di * di;
    ushort2 hs = *(const ushort2*)(h + (size_t)n * 128 + lane * 2);
    float2 b = *(const float2*)(bconv + lane * 2);
    a0 = fmaxf(a0 + sl * bf2f(hs.x) + b.x, 0.f);
    a1 = fmaxf(a1 + sl * bf2f(hs.y) + b.y, 0.f);
    ushort2 o;
    o.x = f2bf(a0);
    o.y = f2bf(a1);
    *(ushort2*)(h2 + (size_t)n * 128 + lane * 2) = o;
}

// ---------------- GEMM: out[M x 128] = A[M x 128] @ W[128 x 128]^T ----------------
template <bool IN_BF16, bool BIAS, bool RELU, bool OUT_BF16>
__global__ __launch_bounds__(256) void gemm_k128(const void* __restrict__ Ain,
                                                 const float* __restrict__ W,
                                                 const float* __restrict__ bias,
                                                 void* __restrict__ Out, int M) {
    __shared__ __align__(16) unsigned short Wl[128 * 136];
    const int tid = threadIdx.x;
#pragma unroll
    for (int i = 0; i < 16; ++i) {
        int e4 = i * 256 + tid;
        float4 v = ((const float4*)W)[e4];
        int e = e4 * 4;
        int r = e >> 7, c = e & 127;
        unsigned short* p = &Wl[r * 136 + c];
        p[0] = f2bf(v.x); p[1] = f2bf(v.y); p[2] = f2bf(v.z); p[3] = f2bf(v.w);
    }
    __syncthreads();

    const int wave = tid >> 6, lane = tid & 63;
    const int m = lane & 15, quad = lane >> 4;
    const int rowBase = blockIdx.x * 64 + wave * 16;
    int arow = rowBase + m;
    int arowc = arow < M ? arow : (M - 1);

    bf16x8 afrag[4];
    if constexpr (IN_BF16) {
        const unsigned short* A = (const unsigned short*)Ain;
        const unsigned short* pa = A + (size_t)arowc * 128 + quad * 8;
#pragma unroll
        for (int kc = 0; kc < 4; ++kc)
            afrag[kc] = *(const bf16x8*)(pa + kc * 32);
    } else {
        const float* A = (const float*)Ain;
        const float* pa = A + (size_t)arowc * 128 + quad * 8;
#pragma unroll
        for (int kc = 0; kc < 4; ++kc) {
            float4 v0 = *(const float4*)(pa + kc * 32);
            float4 v1 = *(const float4*)(pa + kc * 32 + 4);
            bf16x8 f;
            f[0] = (short)f2bf(v0.x); f[1] = (short)f2bf(v0.y);
            f[2] = (short)f2bf(v0.z); f[3] = (short)f2bf(v0.w);
            f[4] = (short)f2bf(v1.x); f[5] = (short)f2bf(v1.y);
            f[6] = (short)f2bf(v1.z); f[7] = (short)f2bf(v1.w);
            afrag[kc] = f;
        }
    }

#pragma unroll
    for (int nt = 0; nt < 8; ++nt) {
        f32x4 acc = {0.f, 0.f, 0.f, 0.f};
        const unsigned short* wb = &Wl[(nt * 16 + m) * 136 + quad * 8];
#pragma unroll
        for (int kc = 0; kc < 4; ++kc) {
            bf16x8 bfrag = *(const bf16x8*)(wb + kc * 32);
            acc = __builtin_amdgcn_mfma_f32_16x16x32_bf16(afrag[kc], bfrag, acc, 0, 0, 0);
        }
        const int col = nt * 16 + m;
        float bv = 0.f;
        if constexpr (BIAS) bv = bias[col];
#pragma unroll
        for (int r = 0; r < 4; ++r) {
            int row = rowBase + quad * 4 + r;
            if (row < M) {
                float v = acc[r] + bv;
                if constexpr (RELU) v = fmaxf(v, 0.f);
                if constexpr (OUT_BF16)
                    ((unsigned short*)Out)[(size_t)row * 128 + col] = f2bf(v);
                else
                    ((float*)Out)[(size_t)row * 128 + col] = v;
            }
        }
    }
}

extern "C" void kernel_launch(void* const* d_in, const int* in_sizes, int n_in,
                              void* d_out, int out_size, void* d_ws, size_t ws_size,
                              hipStream_t stream) {
    const float* x  = (const float*)d_in[0];
    const int* ei   = (const int*)d_in[1];
    const float* ew = (const float*)d_in[2];
    const float* Wc = (const float*)d_in[3];
    const float* bc = (const float*)d_in[4];
    const float* Wf = (const float*)d_in[5];
    const float* bf = (const float*)d_in[6];
    const float* W2 = (const float*)d_in[7];
    const float* b2 = (const float*)d_in[8];
    float* out = (float*)d_out;

    const int N = in_sizes[0] / 128;
    const int E = in_sizes[2];

    auto align256 = [](size_t v) { return (v + 255) & ~(size_t)255; };
    char* ws = (char*)d_ws;
    size_t off = 0;
    float* deg = (float*)(ws + off); off += align256((size_t)N * 4);   // -> dinv
    int* cnt   = (int*)(ws + off);   off += align256((size_t)N * 4);   // -> cursor
    int* rowPtr= (int*)(ws + off);   off += align256((size_t)(N + 1) * 4);
    int* bsum  = (int*)(ws + off);   off += align256(1024 * 4);
    unsigned short* h  = (unsigned short*)(ws + off); off += (size_t)N * 256;
    unsigned short* h2 = (unsigned short*)(ws + off);
    int2* csr = (int2*)out;  // 8B*E = 25.6MB <= 51.2MB; consumed before final GEMM

    const int nBN = (N + 255) / 256;
    const int nBE = (E + 255) / 256;

    init_k<<<nBN, 256, 0, stream>>>(deg, cnt, N);
    hist_k<<<nBE, 256, 0, stream>>>(ei, ew, cnt, deg, E);
    scan1_k<<<nBN, 256, 0, stream>>>(cnt, rowPtr, bsum, N);
    scan2_k<<<1, 1024, 0, stream>>>(bsum, nBN);
    scan3_k<<<nBN, 256, 0, stream>>>(rowPtr, bsum, cnt, deg, N, E);

    // h = bf16(x @ W_conv^T)
    gemm_k128<false, false, false, true>
        <<<(N + 63) / 64, 256, 0, stream>>>(x, Wc, nullptr, h, N);

    fill_k<<<nBE, 256, 0, stream>>>(ei, ew, deg, cnt, csr, E);

    agg_k<<<(N + 3) / 4, 256, 0, stream>>>(rowPtr, csr, h, deg, bc, h2, N);

    // h = bf16(relu(h2 @ W_fc^T + b_fc))
    gemm_k128<true, true, true, true>
        <<<(N + 63) / 64, 256, 0, stream>>>(h2, Wf, bf, h, N);

    // out = h @ W_fc2^T + b_fc2
    gemm_k128<true, true, false, false>
        <<<(N + 63) / 64, 256, 0, stream>>>(h, W2, b2, out, N);
}

// Round 3
// 723.528 us; speedup vs baseline: 7.8499x; 1.2534x over previous
//
#include <hip/hip_runtime.h>
#include <hip/hip_bf16.h>

typedef short bf16x8 __attribute__((ext_vector_type(8)));
typedef float f32x4 __attribute__((ext_vector_type(4)));

__device__ __forceinline__ unsigned short f2bf(float f) {
    unsigned int u = __float_as_uint(f);
    u = (u + 0x7FFFu + ((u >> 16) & 1u)) >> 16;
    return (unsigned short)u;
}
__device__ __forceinline__ float bf2f(unsigned short h) {
    return __uint_as_float(((unsigned int)h) << 16);
}

// ---------------- init: deg = 1 (self-loop weight), cnt = 0 ----------------
__global__ __launch_bounds__(256) void init_k(float* __restrict__ deg,
                                              int* __restrict__ cnt, int N) {
    int i = blockIdx.x * 256 + threadIdx.x;
    if (i < N) { deg[i] = 1.0f; cnt[i] = 0; }
}

// ---------------- convert 3 weight matrices fp32 -> bf16 ----------------
__global__ __launch_bounds__(256) void cvtW_k(const float* __restrict__ Wc,
                                              const float* __restrict__ Wf,
                                              const float* __restrict__ W2,
                                              unsigned short* __restrict__ Wb) {
    int i = blockIdx.x * 256 + threadIdx.x;  // 3*16384 elements
    if (i >= 3 * 16384) return;
    const float* src = (i < 16384) ? Wc : (i < 32768 ? Wf : W2);
    int j = i & 16383;
    Wb[i] = f2bf(src[j]);
}

// ---------------- histogram by dst + weighted degree ----------------
__global__ __launch_bounds__(256) void hist_k(const int* __restrict__ ei,
                                              const float* __restrict__ ew,
                                              int* __restrict__ cnt,
                                              float* __restrict__ deg, int E) {
    int e = blockIdx.x * 256 + threadIdx.x;
    if (e < E) {
        int dst = ei[E + e];
        atomicAdd(&cnt[dst], 1);
        unsafeAtomicAdd(&deg[dst], ew[e]);
    }
}

// ---------------- scan pass 1 ----------------
__global__ __launch_bounds__(256) void scan1_k(const int* __restrict__ cnt,
                                               int* __restrict__ rowPtr,
                                               int* __restrict__ bsum, int N) {
    __shared__ int s[256];
    int t = threadIdx.x;
    int i = blockIdx.x * 256 + t;
    int v = (i < N) ? cnt[i] : 0;
    s[t] = v;
    __syncthreads();
#pragma unroll
    for (int off = 1; off < 256; off <<= 1) {
        int x = (t >= off) ? s[t - off] : 0;
        __syncthreads();
        s[t] += x;
        __syncthreads();
    }
    if (i < N) rowPtr[i] = s[t] - v;
    if (t == 255) bsum[blockIdx.x] = s[255];
}

// ---------------- scan pass 2 ----------------
__global__ __launch_bounds__(1024) void scan2_k(int* __restrict__ bsum, int nB) {
    __shared__ int s[1024];
    int t = threadIdx.x;
    int v = (t < nB) ? bsum[t] : 0;
    s[t] = v;
    __syncthreads();
#pragma unroll
    for (int off = 1; off < 1024; off <<= 1) {
        int x = (t >= off) ? s[t - off] : 0;
        __syncthreads();
        s[t] += x;
        __syncthreads();
    }
    if (t < nB) bsum[t] = s[t] - v;
}

// ---------------- scan pass 3: offsets, cursor, dinv ----------------
__global__ __launch_bounds__(256) void scan3_k(int* __restrict__ rowPtr,
                                               const int* __restrict__ bsum,
                                               int* __restrict__ cursor,
                                               float* __restrict__ deg,
                                               int N, int E) {
    int i = blockIdx.x * 256 + threadIdx.x;
    if (i < N) {
        int rp = rowPtr[i] + bsum[blockIdx.x];
        rowPtr[i] = rp;
        cursor[i] = rp;
        float d = deg[i];
        deg[i] = d > 0.f ? rsqrtf(d) : 0.f;
    }
    if (i == 0) rowPtr[N] = E;
}

// ---------------- fill: csr[pos] = {src, norm} binned by dst ----------------
__global__ __launch_bounds__(256) void fill_k(const int* __restrict__ ei,
                                              const float* __restrict__ ew,
                                              const float* __restrict__ dinv,
                                              int* __restrict__ cursor,
                                              int2* __restrict__ csr, int E) {
    int e = blockIdx.x * 256 + threadIdx.x;
    if (e >= E) return;
    int src = ei[e];
    int dst = ei[E + e];
    float nrm = dinv[src] * ew[e] * dinv[dst];
    int p = atomicAdd(&cursor[dst], 1);
    csr[p] = make_int2(src, __float_as_int(nrm));
}

// ---------------- aggregate: one wave/node, 16 lanes/edge, 8 edges in flight ----------------
// h2[n] = bf16(relu( sum_bin h[src]*nrm + dinv[n]^2*h[n] + b_conv ))
__global__ __launch_bounds__(256) void agg_k(const int* __restrict__ rowPtr,
                                             const int2* __restrict__ csr,
                                             const unsigned short* __restrict__ h,
                                             const float* __restrict__ dinv,
                                             const float* __restrict__ bconv,
                                             unsigned short* __restrict__ h2, int N) {
    int lane = threadIdx.x & 63;
    int n = blockIdx.x * 4 + (threadIdx.x >> 6);
    if (n >= N) return;
    int s = rowPtr[n], e = rowPtr[n + 1];
    const int g = lane >> 4;         // edge slot 0..3
    const int c = (lane & 15) * 8;   // channel base (8 ch/lane)
    float acc[8] = {0.f, 0.f, 0.f, 0.f, 0.f, 0.f, 0.f, 0.f};

    for (int j = s; j < e; j += 8) {
        int j0 = j + g;
        int j1 = j + 4 + g;
        int2 p0 = csr[j0 < e ? j0 : (e - 1)];
        int2 p1 = csr[j1 < e ? j1 : (e - 1)];
        float n0 = (j0 < e) ? __int_as_float(p0.y) : 0.f;
        float n1 = (j1 < e) ? __int_as_float(p1.y) : 0.f;
        bf16x8 v0 = *(const bf16x8*)(h + (size_t)p0.x * 128 + c);
        bf16x8 v1 = *(const bf16x8*)(h + (size_t)p1.x * 128 + c);
#pragma unroll
        for (int k = 0; k < 8; ++k) acc[k] += bf2f((unsigned short)v0[k]) * n0;
#pragma unroll
        for (int k = 0; k < 8; ++k) acc[k] += bf2f((unsigned short)v1[k]) * n1;
    }

    // fold the 4 edge slots: lanes {l, l^16, l^32, l^48} share channel group
#pragma unroll
    for (int k = 0; k < 8; ++k) {
        float v = acc[k];
        v += __shfl_xor(v, 16, 64);
        v += __shfl_xor(v, 32, 64);
        acc[k] = v;
    }

    if (g == 0) {  // lanes 0..15: epilogue for 8 channels each
        float di = dinv[n];
        float sl = di * di;
        bf16x8 hs = *(const bf16x8*)(h + (size_t)n * 128 + c);
        bf16x8 o;
#pragma unroll
        for (int k = 0; k < 8; ++k) {
            float v = acc[k] + sl * bf2f((unsigned short)hs[k]) + bconv[c + k];
            o[k] = (short)f2bf(fmaxf(v, 0.f));
        }
        *(bf16x8*)(h2 + (size_t)n * 128 + c) = o;
    }
}

// ---------------- GEMM: out[M x 128] = A[M x 128] @ Wb[128 x 128]^T (W bf16) ----------------
template <bool IN_BF16, bool BIAS, bool RELU, bool OUT_BF16>
__global__ __launch_bounds__(256) void gemm_k128(const void* __restrict__ Ain,
                                                 const unsigned short* __restrict__ Wb,
                                                 const float* __restrict__ bias,
                                                 void* __restrict__ Out, int M) {
    __shared__ __align__(16) unsigned short Wl[128 * 136];
    const int tid = threadIdx.x;
#pragma unroll
    for (int i = 0; i < 8; ++i) {
        int e8 = i * 256 + tid;          // ushort8 index (2048 total)
        int e = e8 * 8;
        int r = e >> 7, cc = e & 127;
        *(bf16x8*)&Wl[r * 136 + cc] = ((const bf16x8*)Wb)[e8];
    }
    __syncthreads();

    const int wave = tid >> 6, lane = tid & 63;
    const int m = lane & 15, quad = lane >> 4;
    const int rowBase = blockIdx.x * 64 + wave * 16;
    int arow = rowBase + m;
    int arowc = arow < M ? arow : (M - 1);

    bf16x8 afrag[4];
    if constexpr (IN_BF16) {
        const unsigned short* A = (const unsigned short*)Ain;
        const unsigned short* pa = A + (size_t)arowc * 128 + quad * 8;
#pragma unroll
        for (int kc = 0; kc < 4; ++kc)
            afrag[kc] = *(const bf16x8*)(pa + kc * 32);
    } else {
        const float* A = (const float*)Ain;
        const float* pa = A + (size_t)arowc * 128 + quad * 8;
#pragma unroll
        for (int kc = 0; kc < 4; ++kc) {
            float4 v0 = *(const float4*)(pa + kc * 32);
            float4 v1 = *(const float4*)(pa + kc * 32 + 4);
            bf16x8 f;
            f[0] = (short)f2bf(v0.x); f[1] = (short)f2bf(v0.y);
            f[2] = (short)f2bf(v0.z); f[3] = (short)f2bf(v0.w);
            f[4] = (short)f2bf(v1.x); f[5] = (short)f2bf(v1.y);
            f[6] = (short)f2bf(v1.z); f[7] = (short)f2bf(v1.w);
            afrag[kc] = f;
        }
    }

#pragma unroll
    for (int nt = 0; nt < 8; ++nt) {
        f32x4 acc = {0.f, 0.f, 0.f, 0.f};
        const unsigned short* wb = &Wl[(nt * 16 + m) * 136 + quad * 8];
#pragma unroll
        for (int kc = 0; kc < 4; ++kc) {
            bf16x8 bfrag = *(const bf16x8*)(wb + kc * 32);
            acc = __builtin_amdgcn_mfma_f32_16x16x32_bf16(afrag[kc], bfrag, acc, 0, 0, 0);
        }
        const int col = nt * 16 + m;
        float bv = 0.f;
        if constexpr (BIAS) bv = bias[col];
#pragma unroll
        for (int r = 0; r < 4; ++r) {
            int row = rowBase + quad * 4 + r;
            if (row < M) {
                float v = acc[r] + bv;
                if constexpr (RELU) v = fmaxf(v, 0.f);
                if constexpr (OUT_BF16)
                    ((unsigned short*)Out)[(size_t)row * 128 + col] = f2bf(v);
                else
                    ((float*)Out)[(size_t)row * 128 + col] = v;
            }
        }
    }
}

extern "C" void kernel_launch(void* const* d_in, const int* in_sizes, int n_in,
                              void* d_out, int out_size, void* d_ws, size_t ws_size,
                              hipStream_t stream) {
    const float* x  = (const float*)d_in[0];
    const int* ei   = (const int*)d_in[1];
    const float* ew = (const float*)d_in[2];
    const float* Wc = (const float*)d_in[3];
    const float* bc = (const float*)d_in[4];
    const float* Wf = (const float*)d_in[5];
    const float* bf = (const float*)d_in[6];
    const float* W2 = (const float*)d_in[7];
    const float* b2 = (const float*)d_in[8];
    float* out = (float*)d_out;

    const int N = in_sizes[0] / 128;
    const int E = in_sizes[2];

    auto align256 = [](size_t v) { return (v + 255) & ~(size_t)255; };
    char* ws = (char*)d_ws;
    size_t off = 0;
    float* deg = (float*)(ws + off); off += align256((size_t)N * 4);   // -> dinv
    int* cnt   = (int*)(ws + off);   off += align256((size_t)N * 4);   // -> cursor
    int* rowPtr= (int*)(ws + off);   off += align256((size_t)(N + 1) * 4);
    int* bsum  = (int*)(ws + off);   off += align256(1024 * 4);
    unsigned short* Wball = (unsigned short*)(ws + off); off += align256(3 * 16384 * 2);
    unsigned short* h  = (unsigned short*)(ws + off); off += (size_t)N * 256;
    unsigned short* h2 = (unsigned short*)(ws + off);
    int2* csr = (int2*)out;  // 25.6MB in d_out (51.2MB); consumed before final GEMM

    unsigned short* Wcb = Wball;
    unsigned short* Wfb = Wball + 16384;
    unsigned short* W2b = Wball + 32768;

    const int nBN = (N + 255) / 256;
    const int nBE = (E + 255) / 256;

    init_k<<<nBN, 256, 0, stream>>>(deg, cnt, N);
    cvtW_k<<<192, 256, 0, stream>>>(Wc, Wf, W2, Wball);
    hist_k<<<nBE, 256, 0, stream>>>(ei, ew, cnt, deg, E);
    scan1_k<<<nBN, 256, 0, stream>>>(cnt, rowPtr, bsum, N);
    scan2_k<<<1, 1024, 0, stream>>>(bsum, nBN);
    scan3_k<<<nBN, 256, 0, stream>>>(rowPtr, bsum, cnt, deg, N, E);

    // h = bf16(x @ W_conv^T)
    gemm_k128<false, false, false, true>
        <<<(N + 63) / 64, 256, 0, stream>>>(x, Wcb, nullptr, h, N);

    fill_k<<<nBE, 256, 0, stream>>>(ei, ew, deg, cnt, csr, E);

    agg_k<<<(N + 3) / 4, 256, 0, stream>>>(rowPtr, csr, h, deg, bc, h2, N);

    // h = bf16(relu(h2 @ W_fc^T + b_fc))
    gemm_k128<true, true, true, true>
        <<<(N + 63) / 64, 256, 0, stream>>>(h2, Wfb, bf, h, N);

    // out = h @ W_fc2^T + b_fc2
    gemm_k128<true, true, false, false>
        <<<(N + 63) / 64, 256, 0, stream>>>(h, W2b, b2, out, N);
}